// Round 8
// baseline (195.679 us; speedup 1.0000x reference)
//
#include <hip/hip_runtime.h>
#include <stdint.h>

#define HH 8192           // B*H = 16*512 strip height
#define WW 512            // width
#define WPR 8             // uint64 words per row (512/64)
#define TG22F 0.4142135623730951f
#define NROUND 8          // cap; early-exits on convergence
#define NBLK 32           // hysteresis grid (co-resident: 32 blocks << 256 CUs)

// ---- workspace layout (bytes) ----
// buf (strong, in-place) : 512 KiB @ 0
// weak bitmap            : 512 KiB @ 524288
// flags (16 ints)        : 64 B    @ 1048576
//   flags[0..7]  = per-round "grew" indicators
//   flags[8..15] = per-round grid-barrier arrive counters (single-use, no reset)

__device__ __forceinline__ float to_img(float v) {
    float t = floorf((v + 1.0f) * 0.5f * 255.0f);
    return fminf(fmaxf(t, 0.0f), 255.0f);
}

// Fill all bits of runs of `w` that contain at least one bit of `s`.
__device__ __forceinline__ uint64_t runfill(uint64_t s, uint64_t w) {
    uint64_t sw = s & w;
    uint64_t up = ((sw + w) ^ w) & w;
    uint64_t rs = __brevll(sw);
    uint64_t rw = __brevll(w);
    uint64_t dn = __brevll(((rs + rw) ^ rw) & rw);
    return up | dn | sw;
}

// 64-bit shuffles via two 32-bit halves (avoid 64-bit shfl overloads).
__device__ __forceinline__ uint64_t shfl_up64(uint64_t v, int d) {
    int lo = __shfl_up((int)(uint32_t)v, d, 64);
    int hi = __shfl_up((int)(uint32_t)(v >> 32), d, 64);
    return ((uint64_t)(uint32_t)hi << 32) | (uint32_t)lo;
}
__device__ __forceinline__ uint64_t shfl_dn64(uint64_t v, int d) {
    int lo = __shfl_down((int)(uint32_t)v, d, 64);
    int hi = __shfl_down((int)(uint32_t)(v >> 32), d, 64);
    return ((uint64_t)(uint32_t)hi << 32) | (uint32_t)lo;
}

// coherent (cache-bypassing) 64-bit load/store at agent scope, no fences
__device__ __forceinline__ uint64_t cload64(const unsigned long long* p) {
    return __hip_atomic_load((const unsigned long long*)p, __ATOMIC_RELAXED,
                             __HIP_MEMORY_SCOPE_AGENT);
}
__device__ __forceinline__ void cstore64(unsigned long long* p, uint64_t v) {
    __hip_atomic_store(p, (unsigned long long)v, __ATOMIC_RELAXED,
                       __HIP_MEMORY_SCOPE_AGENT);
}

// load 10 quantized pixels (cols 8*lane-1 .. 8*lane+8, edge-replicated) of
// one channel/row into a[0..9]. Two coalesced float4 loads + 2 shuffles.
// (verbatim round-7 verified helper)
__device__ __forceinline__ void load_row10(const float* __restrict__ in,
                                           int row, int c, int lane, int a[10]) {
    const float* p = &in[(size_t)((((row >> 9) * 3 + c) << 9) + (row & 511)) << 9];
    const int x0 = lane << 3;
    float4 v0 = *(const float4*)&p[x0];
    float4 v1 = *(const float4*)&p[x0 + 4];
    a[1] = (int)(uint8_t)to_img(v0.x);
    a[2] = (int)(uint8_t)to_img(v0.y);
    a[3] = (int)(uint8_t)to_img(v0.z);
    a[4] = (int)(uint8_t)to_img(v0.w);
    a[5] = (int)(uint8_t)to_img(v1.x);
    a[6] = (int)(uint8_t)to_img(v1.y);
    a[7] = (int)(uint8_t)to_img(v1.z);
    a[8] = (int)(uint8_t)to_img(v1.w);
    int l = __shfl_up(a[8], 1, 64);
    a[0] = (lane == 0) ? a[1] : l;      // col -1 -> replicate col 0
    int r = __shfl_down(a[1], 1, 64);
    a[9] = (lane == 63) ? a[8] : r;     // col 512 -> replicate col 511
}

// Kernel 1 (NEW): fused quantize + Sobel + channel argmax + NMS, one WAVE per
// output row, 8 px/lane, pure registers (no LDS, no barriers). Each wave
// computes Sobel magnitude for rows y-1, y, y+1 (channel running-max ==
// argmax'd mag; dir kept only for center row) from input rows y-2..y+2
// (strip-replicate clamp, arithmetic verbatim from the verified kernels),
// then applies the verbatim k_nms decision on register mags: out-of-strip
// neighbor rows -> 0, x<0 / x>=WW -> 0 (via 6 lane-edge shuffles). Emits
// strong/weak bitmaps directly; the packed u16 array is gone.
__global__ void k_sobnms(const float* __restrict__ in,
                         unsigned long long* __restrict__ strongB,
                         unsigned long long* __restrict__ weakB,
                         int* __restrict__ flags) {
    if (blockIdx.x == 0 && threadIdx.x < 16) flags[threadIdx.x] = 0;
    const int lane = threadIdx.x & 63;
    const int y = (blockIdx.x << 2) + (threadIdx.x >> 6);

    // input row indices, strip-level replicate clamp (verbatim semantics)
    const int r0 = (y - 2 < 0) ? 0 : y - 2;
    const int r1 = (y - 1 < 0) ? 0 : y - 1;
    const int r3 = (y + 1 >= HH) ? HH - 1 : y + 1;
    const int r4 = (y + 2 >= HH) ? HH - 1 : y + 2;

    int magU[8], magC[8], magD[8], bgx[8], bgy[8];
    #pragma unroll
    for (int j = 0; j < 8; ++j) {
        magU[j] = -1; magC[j] = -1; magD[j] = -1; bgx[j] = 0; bgy[j] = 0;
    }

    #pragma unroll
    for (int c = 0; c < 3; ++c) {
        int a0[10], a1[10], a2[10], a3[10], a4[10];
        load_row10(in, r0, c, lane, a0);
        load_row10(in, r1, c, lane, a1);
        load_row10(in, y,  c, lane, a2);
        load_row10(in, r3, c, lane, a3);
        load_row10(in, r4, c, lane, a4);
        int vsU[10], vsC[10], vsD[10];
        #pragma unroll
        for (int i = 0; i < 10; ++i) {
            vsU[i] = a0[i] + 2 * a1[i] + a2[i];
            vsC[i] = a1[i] + 2 * a2[i] + a3[i];
            vsD[i] = a2[i] + 2 * a3[i] + a4[i];
        }
        #pragma unroll
        for (int j = 0; j < 8; ++j) {
            // mag row y-1 (gy from rows y-2 / y)
            int gxu = vsU[j + 2] - vsU[j];
            int gyu = (a2[j] + 2 * a2[j + 1] + a2[j + 2]) - (a0[j] + 2 * a0[j + 1] + a0[j + 2]);
            int mgu = abs(gxu) + abs(gyu);
            if (mgu > magU[j]) magU[j] = mgu;
            // mag row y (center; keep gx/gy for dir)
            int gxc = vsC[j + 2] - vsC[j];
            int gyc = (a3[j] + 2 * a3[j + 1] + a3[j + 2]) - (a1[j] + 2 * a1[j + 1] + a1[j + 2]);
            int mgc = abs(gxc) + abs(gyc);
            if (mgc > magC[j]) { magC[j] = mgc; bgx[j] = gxc; bgy[j] = gyc; }
            // mag row y+1 (gy from rows y / y+2)
            int gxd = vsD[j + 2] - vsD[j];
            int gyd = (a4[j] + 2 * a4[j + 1] + a4[j + 2]) - (a2[j] + 2 * a2[j + 1] + a2[j + 2]);
            int mgd = abs(gxd) + abs(gyd);
            if (mgd > magD[j]) magD[j] = mgd;
        }
    }

    // NMS zero-pad semantics: out-of-strip neighbor rows read as 0
    if (y == 0) {
        #pragma unroll
        for (int j = 0; j < 8; ++j) magU[j] = 0;
    }
    if (y == HH - 1) {
        #pragma unroll
        for (int j = 0; j < 8; ++j) magD[j] = 0;
    }

    // lane-edge neighbor mags; x<0 / x>=WW -> 0 (verbatim k_nms semantics)
    int oL = __shfl_up(magC[7], 1, 64);   if (lane == 0)  oL = 0;
    int uL = __shfl_up(magU[7], 1, 64);   if (lane == 0)  uL = 0;
    int dL = __shfl_up(magD[7], 1, 64);   if (lane == 0)  dL = 0;
    int oR = __shfl_down(magC[0], 1, 64); if (lane == 63) oR = 0;
    int uR = __shfl_down(magU[0], 1, 64); if (lane == 63) uR = 0;
    int dR = __shfl_down(magD[0], 1, 64); if (lane == 63) dR = 0;

    uint32_t sb = 0, wb = 0;
    #pragma unroll
    for (int j = 0; j < 8; ++j) {
        int m = magC[j];
        float axf = (float)abs(bgx[j]);
        float ayf = (float)abs(bgy[j]);
        int dir;
        if (ayf < TG22F * axf)      dir = 0;
        else if (ayf * TG22F > axf) dir = 1;
        else                        dir = (bgx[j] * bgy[j] >= 0) ? 2 : 3;
        int Om1 = (j == 0) ? oL : magC[j == 0 ? 0 : j - 1];
        int Op1 = (j == 7) ? oR : magC[j == 7 ? 7 : j + 1];
        int Ui  = magU[j];
        int Um1 = (j == 0) ? uL : magU[j == 0 ? 0 : j - 1];
        int Up1 = (j == 7) ? uR : magU[j == 7 ? 7 : j + 1];
        int Di  = magD[j];
        int Dm1 = (j == 0) ? dL : magD[j == 0 ? 0 : j - 1];
        int Dp1 = (j == 7) ? dR : magD[j == 7 ? 7 : j + 1];
        // dir0:(0,-1) dir1:(-1,0) dir2:(-1,-1) dir3:(-1,+1); n1=+d1, n2=-d1
        int n1 = (dir == 0) ? Om1 : (dir == 1) ? Ui : (dir == 2) ? Um1 : Up1;
        int n2 = (dir == 0) ? Op1 : (dir == 1) ? Di : (dir == 2) ? Dp1 : Dm1;
        bool keep = (m > n1) && (m >= n2);
        if (keep && m > 200) sb |= 1u << j;
        if (keep && m > 100) wb |= 1u << j;
    }

    // pack 64 lanes x 8 bits -> 8 u64 words per row via shuffles (verbatim)
    const int src = (lane & 7) << 3;
    uint64_t wordS = 0, wordW = 0;
    #pragma unroll
    for (int i = 0; i < 8; ++i) {
        wordS |= (uint64_t)(uint32_t)__shfl((int)sb, src + i, 64) << (i * 8);
        wordW |= (uint64_t)(uint32_t)__shfl((int)wb, src + i, 64) << (i * 8);
    }
    if (lane < 8)       strongB[y * WPR + lane] = wordS;
    else if (lane < 16) weakB[y * WPR + (lane - 8)] = wordW;
}

// Kernel 2: ALL hysteresis rounds in ONE kernel (verbatim round-5 verified).
__global__ void __launch_bounds__(256) k_hyst(
        const unsigned long long* __restrict__ weakB,
        unsigned long long* __restrict__ buf,
        int* __restrict__ flags)
{
    const int lane = threadIdx.x & 63;
    const int wave = (blockIdx.x << 2) + (threadIdx.x >> 6);   // 0..127
    const int base = ((wave << 6) + lane) * WPR;               // own row

    uint64_t own[8], wk[8];
    #pragma unroll
    for (int k = 0; k < 8; ++k) { wk[k] = weakB[base + k]; own[k] = buf[base + k]; }

    uint64_t hspu[8], hspd[8];
    #pragma unroll
    for (int k = 0; k < 8; ++k) { hspu[k] = 0; hspd[k] = 0; }

    auto load_halo = [&]() {
        uint64_t h[8];
        if (lane == 0 && wave > 0) {
            #pragma unroll
            for (int k = 0; k < 8; ++k) h[k] = cload64(&buf[base - WPR + k]);
            #pragma unroll
            for (int k = 0; k < 8; ++k) {
                uint64_t a = h[k] | (h[k] << 1) | (h[k] >> 1);
                if (k > 0) a |= h[k - 1] >> 63;
                if (k < 7) a |= h[k + 1] << 63;
                hspu[k] = a;
            }
        }
        if (lane == 63 && wave < 127) {
            #pragma unroll
            for (int k = 0; k < 8; ++k) h[k] = cload64(&buf[base + WPR + k]);
            #pragma unroll
            for (int k = 0; k < 8; ++k) {
                uint64_t a = h[k] | (h[k] << 1) | (h[k] >> 1);
                if (k > 0) a |= h[k - 1] >> 63;
                if (k < 7) a |= h[k + 1] << 63;
                hspd[k] = a;
            }
        }
    };
    load_halo();

    bool grewAny = false;
    for (int r = 0; r < NROUND; ++r) {
        bool grew = false;
        for (;;) {
            uint64_t sp[8];
            #pragma unroll
            for (int k = 0; k < 8; ++k) {
                uint64_t h = own[k] | (own[k] << 1) | (own[k] >> 1);
                if (k > 0) h |= own[k - 1] >> 63;
                if (k < 7) h |= own[k + 1] << 63;
                sp[k] = h;
            }
            uint64_t su[8], sd[8];
            #pragma unroll
            for (int k = 0; k < 8; ++k) {
                su[k] = shfl_up64(sp[k], 1);
                sd[k] = shfl_dn64(sp[k], 1);
            }
            if (lane == 0) {
                #pragma unroll
                for (int k = 0; k < 8; ++k) su[k] = hspu[k];
            }
            if (lane == 63) {
                #pragma unroll
                for (int k = 0; k < 8; ++k) sd[k] = hspd[k];
            }
            uint32_t ch = 0;
            #pragma unroll
            for (int k = 0; k < 8; ++k) {
                uint64_t acc = sp[k] | su[k] | sd[k];
                uint64_t nv = runfill(own[k] | (acc & wk[k]), wk[k]);
                ch |= (uint32_t)(nv != own[k]);
                own[k] = nv;
            }
            if (ch) grew = true;
            if (__ballot(ch ? 1 : 0) == 0ull) break;   // wave-uniform
        }
        grewAny |= grew;

        if (grew && lane == 0)
            __hip_atomic_store(&flags[r], 1, __ATOMIC_RELAXED, __HIP_MEMORY_SCOPE_AGENT);
        if (lane == 0 || lane == 63) {
            #pragma unroll
            for (int k = 0; k < 8; ++k) cstore64(&buf[base + k], own[k]);
        }
        __syncthreads();
        if (threadIdx.x == 0) {
            __hip_atomic_fetch_add(&flags[8 + r], 1, __ATOMIC_RELAXED, __HIP_MEMORY_SCOPE_AGENT);
            while (__hip_atomic_load(&flags[8 + r], __ATOMIC_RELAXED, __HIP_MEMORY_SCOPE_AGENT) < NBLK)
                __builtin_amdgcn_s_sleep(2);
        }
        __syncthreads();

        if (__hip_atomic_load(&flags[r], __ATOMIC_RELAXED, __HIP_MEMORY_SCOPE_AGENT) == 0)
            break;
        if (r + 1 < NROUND) load_halo();
    }

    if (__ballot(grewAny ? 1 : 0) != 0ull) {
        #pragma unroll
        for (int k = 0; k < 8; ++k) buf[base + k] = own[k];
    }
}

// Kernel 3: expand bitmap -> (16,3,512,512) f32 output in {-1,+1}, float4.
__global__ void k_out(const unsigned long long* __restrict__ result, float* __restrict__ out) {
    int t = blockIdx.x * blockDim.x + threadIdx.x;
    int b = t >> 16;
    int r = t & 65535;
    int h = r >> 7;
    int w = (r & 127) << 2;
    int y = (b << 9) + h;
    unsigned long long word = result[y * WPR + (w >> 6)];
    int sh = w & 63;
    float4 v;
    v.x = ((word >> (sh + 0)) & 1ull) ? 1.0f : -1.0f;
    v.y = ((word >> (sh + 1)) & 1ull) ? 1.0f : -1.0f;
    v.z = ((word >> (sh + 2)) & 1ull) ? 1.0f : -1.0f;
    v.w = ((word >> (sh + 3)) & 1ull) ? 1.0f : -1.0f;
    int base = (b * 3) << 18;
    int off = (h << 9) + w;
    *(float4*)&out[base + off] = v;
    *(float4*)&out[base + 262144 + off] = v;
    *(float4*)&out[base + 524288 + off] = v;
}

extern "C" void kernel_launch(void* const* d_in, const int* in_sizes, int n_in,
                              void* d_out, int out_size, void* d_ws, size_t ws_size,
                              hipStream_t stream) {
    const float* x = (const float*)d_in[0];
    float* out = (float*)d_out;
    char* ws = (char*)d_ws;

    unsigned long long* buf   = (unsigned long long*)(ws);
    unsigned long long* weakB = (unsigned long long*)(ws + 524288);
    int* flags                = (int*)(ws + 1048576);

    k_sobnms<<<2048, 256, 0, stream>>>(x, buf, weakB, flags);
    k_hyst<<<NBLK, 256, 0, stream>>>(weakB, buf, flags);
    k_out<<<4096, 256, 0, stream>>>(buf, out);
}

// Round 9
// 128.834 us; speedup vs baseline: 1.5188x; 1.5188x over previous
//
#include <hip/hip_runtime.h>
#include <stdint.h>

#define HH 8192           // B*H = 16*512 strip height
#define WW 512            // width
#define WPR 8             // uint64 words per row (512/64)
#define TG22F 0.4142135623730951f
#define NROUND 8          // cap; early-exits on convergence
#define NBLK 32           // hysteresis grid (co-resident: 32 blocks << 256 CUs)

// ---- workspace layout (bytes) ----
// buf (strong, in-place) : 512 KiB @ 0
// weak bitmap            : 512 KiB @ 524288
// flags (16 ints)        : 64 B    @ 1048576
//   flags[0..7]  = per-round "grew" indicators
//   flags[8..15] = per-round grid-barrier arrive counters (single-use, no reset)

// Quantize. Input is uniform[-1,1): t = ((v+1)*0.5)*255 lies in [0,255.0]
// (v+1 <= 2.0 -> t <= 255.0; v+1 >= 0 -> t >= 0), so cv2's floor+clip equals
// plain float->int truncation. Expression order kept identical to the
// verified to_img (add, then *0.5f, then *255.0f) -> same rounding, same bytes.
__device__ __forceinline__ int to_img_i(float v) {
    return (int)((v + 1.0f) * 0.5f * 255.0f);
}

// Fill all bits of runs of `w` that contain at least one bit of `s`.
__device__ __forceinline__ uint64_t runfill(uint64_t s, uint64_t w) {
    uint64_t sw = s & w;
    uint64_t up = ((sw + w) ^ w) & w;
    uint64_t rs = __brevll(sw);
    uint64_t rw = __brevll(w);
    uint64_t dn = __brevll(((rs + rw) ^ rw) & rw);
    return up | dn | sw;
}

// 64-bit shuffles via two 32-bit halves (avoid 64-bit shfl overloads).
__device__ __forceinline__ uint64_t shfl_up64(uint64_t v, int d) {
    int lo = __shfl_up((int)(uint32_t)v, d, 64);
    int hi = __shfl_up((int)(uint32_t)(v >> 32), d, 64);
    return ((uint64_t)(uint32_t)hi << 32) | (uint32_t)lo;
}
__device__ __forceinline__ uint64_t shfl_dn64(uint64_t v, int d) {
    int lo = __shfl_down((int)(uint32_t)v, d, 64);
    int hi = __shfl_down((int)(uint32_t)(v >> 32), d, 64);
    return ((uint64_t)(uint32_t)hi << 32) | (uint32_t)lo;
}

// coherent (cache-bypassing) 64-bit load/store at agent scope, no fences
__device__ __forceinline__ uint64_t cload64(const unsigned long long* p) {
    return __hip_atomic_load((const unsigned long long*)p, __ATOMIC_RELAXED,
                             __HIP_MEMORY_SCOPE_AGENT);
}
__device__ __forceinline__ void cstore64(unsigned long long* p, uint64_t v) {
    __hip_atomic_store(p, (unsigned long long)v, __ATOMIC_RELAXED,
                       __HIP_MEMORY_SCOPE_AGENT);
}

// load 10 quantized pixels (cols 8*lane-1 .. 8*lane+8, edge-replicated) of
// one channel/row into a[0..9]. Two coalesced float4 loads + 2 shuffles.
__device__ __forceinline__ void load_row10(const float* __restrict__ in,
                                           int row, int c, int lane, int a[10]) {
    const float* p = &in[(size_t)((((row >> 9) * 3 + c) << 9) + (row & 511)) << 9];
    const int x0 = lane << 3;
    float4 v0 = *(const float4*)&p[x0];
    float4 v1 = *(const float4*)&p[x0 + 4];
    a[1] = to_img_i(v0.x);
    a[2] = to_img_i(v0.y);
    a[3] = to_img_i(v0.z);
    a[4] = to_img_i(v0.w);
    a[5] = to_img_i(v1.x);
    a[6] = to_img_i(v1.y);
    a[7] = to_img_i(v1.z);
    a[8] = to_img_i(v1.w);
    int l = __shfl_up(a[8], 1, 64);
    a[0] = (lane == 0) ? a[1] : l;      // col -1 -> replicate col 0
    int r = __shfl_down(a[1], 1, 64);
    a[9] = (lane == 63) ? a[8] : r;     // col 512 -> replicate col 511
}

// Kernel 1: fused quantize + Sobel + channel argmax + NMS, one WAVE per
// output row, 8 px/lane, pure registers. Semantics harness-verified in
// round 8 (absmax=0). __launch_bounds__(256) lifts the default 1024-thread
// VGPR cap (64) that forced round-8's catastrophic scratch spill.
__global__ void __launch_bounds__(256) k_sobnms(
        const float* __restrict__ in,
        unsigned long long* __restrict__ strongB,
        unsigned long long* __restrict__ weakB,
        int* __restrict__ flags) {
    if (blockIdx.x == 0 && threadIdx.x < 16) flags[threadIdx.x] = 0;
    const int lane = threadIdx.x & 63;
    const int y = (blockIdx.x << 2) + (threadIdx.x >> 6);

    // input row indices, strip-level replicate clamp (verbatim semantics)
    const int r0 = (y - 2 < 0) ? 0 : y - 2;
    const int r1 = (y - 1 < 0) ? 0 : y - 1;
    const int r3 = (y + 1 >= HH) ? HH - 1 : y + 1;
    const int r4 = (y + 2 >= HH) ? HH - 1 : y + 2;

    int magU[8], magC[8], magD[8], bgx[8], bgy[8];
    #pragma unroll
    for (int j = 0; j < 8; ++j) {
        magU[j] = -1; magC[j] = -1; magD[j] = -1; bgx[j] = 0; bgy[j] = 0;
    }

    #pragma unroll
    for (int c = 0; c < 3; ++c) {
        int a0[10], a1[10], a2[10], a3[10], a4[10];
        load_row10(in, r0, c, lane, a0);
        load_row10(in, r1, c, lane, a1);
        load_row10(in, y,  c, lane, a2);
        load_row10(in, r3, c, lane, a3);
        load_row10(in, r4, c, lane, a4);
        int vsU[10], vsC[10], vsD[10];
        #pragma unroll
        for (int i = 0; i < 10; ++i) {
            vsU[i] = a0[i] + 2 * a1[i] + a2[i];
            vsC[i] = a1[i] + 2 * a2[i] + a3[i];
            vsD[i] = a2[i] + 2 * a3[i] + a4[i];
        }
        #pragma unroll
        for (int j = 0; j < 8; ++j) {
            // mag row y-1 (gy from rows y-2 / y)
            int gxu = vsU[j + 2] - vsU[j];
            int gyu = (a2[j] + 2 * a2[j + 1] + a2[j + 2]) - (a0[j] + 2 * a0[j + 1] + a0[j + 2]);
            int mgu = abs(gxu) + abs(gyu);
            if (mgu > magU[j]) magU[j] = mgu;
            // mag row y (center; keep gx/gy for dir)
            int gxc = vsC[j + 2] - vsC[j];
            int gyc = (a3[j] + 2 * a3[j + 1] + a3[j + 2]) - (a1[j] + 2 * a1[j + 1] + a1[j + 2]);
            int mgc = abs(gxc) + abs(gyc);
            if (mgc > magC[j]) { magC[j] = mgc; bgx[j] = gxc; bgy[j] = gyc; }
            // mag row y+1 (gy from rows y / y+2)
            int gxd = vsD[j + 2] - vsD[j];
            int gyd = (a4[j] + 2 * a4[j + 1] + a4[j + 2]) - (a2[j] + 2 * a2[j + 1] + a2[j + 2]);
            int mgd = abs(gxd) + abs(gyd);
            if (mgd > magD[j]) magD[j] = mgd;
        }
    }

    // NMS zero-pad semantics: out-of-strip neighbor rows read as 0
    if (y == 0) {
        #pragma unroll
        for (int j = 0; j < 8; ++j) magU[j] = 0;
    }
    if (y == HH - 1) {
        #pragma unroll
        for (int j = 0; j < 8; ++j) magD[j] = 0;
    }

    // lane-edge neighbor mags; x<0 / x>=WW -> 0 (verbatim k_nms semantics)
    int oL = __shfl_up(magC[7], 1, 64);   if (lane == 0)  oL = 0;
    int uL = __shfl_up(magU[7], 1, 64);   if (lane == 0)  uL = 0;
    int dL = __shfl_up(magD[7], 1, 64);   if (lane == 0)  dL = 0;
    int oR = __shfl_down(magC[0], 1, 64); if (lane == 63) oR = 0;
    int uR = __shfl_down(magU[0], 1, 64); if (lane == 63) uR = 0;
    int dR = __shfl_down(magD[0], 1, 64); if (lane == 63) dR = 0;

    uint32_t sb = 0, wb = 0;
    #pragma unroll
    for (int j = 0; j < 8; ++j) {
        int m = magC[j];
        float axf = (float)abs(bgx[j]);
        float ayf = (float)abs(bgy[j]);
        int dir;
        if (ayf < TG22F * axf)      dir = 0;
        else if (ayf * TG22F > axf) dir = 1;
        else                        dir = (bgx[j] * bgy[j] >= 0) ? 2 : 3;
        int Om1 = (j == 0) ? oL : magC[j == 0 ? 0 : j - 1];
        int Op1 = (j == 7) ? oR : magC[j == 7 ? 7 : j + 1];
        int Ui  = magU[j];
        int Um1 = (j == 0) ? uL : magU[j == 0 ? 0 : j - 1];
        int Up1 = (j == 7) ? uR : magU[j == 7 ? 7 : j + 1];
        int Di  = magD[j];
        int Dm1 = (j == 0) ? dL : magD[j == 0 ? 0 : j - 1];
        int Dp1 = (j == 7) ? dR : magD[j == 7 ? 7 : j + 1];
        // dir0:(0,-1) dir1:(-1,0) dir2:(-1,-1) dir3:(-1,+1); n1=+d1, n2=-d1
        int n1 = (dir == 0) ? Om1 : (dir == 1) ? Ui : (dir == 2) ? Um1 : Up1;
        int n2 = (dir == 0) ? Op1 : (dir == 1) ? Di : (dir == 2) ? Dp1 : Dm1;
        bool keep = (m > n1) && (m >= n2);
        if (keep && m > 200) sb |= 1u << j;
        if (keep && m > 100) wb |= 1u << j;
    }

    // pack 64 lanes x 8 bits -> 8 u64 words per row via shuffles (verbatim)
    const int src = (lane & 7) << 3;
    uint64_t wordS = 0, wordW = 0;
    #pragma unroll
    for (int i = 0; i < 8; ++i) {
        wordS |= (uint64_t)(uint32_t)__shfl((int)sb, src + i, 64) << (i * 8);
        wordW |= (uint64_t)(uint32_t)__shfl((int)wb, src + i, 64) << (i * 8);
    }
    if (lane < 8)       strongB[y * WPR + lane] = wordS;
    else if (lane < 16) weakB[y * WPR + (lane - 8)] = wordW;
}

// Kernel 2: ALL hysteresis rounds in ONE kernel (verbatim round-5 verified).
__global__ void __launch_bounds__(256) k_hyst(
        const unsigned long long* __restrict__ weakB,
        unsigned long long* __restrict__ buf,
        int* __restrict__ flags)
{
    const int lane = threadIdx.x & 63;
    const int wave = (blockIdx.x << 2) + (threadIdx.x >> 6);   // 0..127
    const int base = ((wave << 6) + lane) * WPR;               // own row

    uint64_t own[8], wk[8];
    #pragma unroll
    for (int k = 0; k < 8; ++k) { wk[k] = weakB[base + k]; own[k] = buf[base + k]; }

    uint64_t hspu[8], hspd[8];
    #pragma unroll
    for (int k = 0; k < 8; ++k) { hspu[k] = 0; hspd[k] = 0; }

    auto load_halo = [&]() {
        uint64_t h[8];
        if (lane == 0 && wave > 0) {
            #pragma unroll
            for (int k = 0; k < 8; ++k) h[k] = cload64(&buf[base - WPR + k]);
            #pragma unroll
            for (int k = 0; k < 8; ++k) {
                uint64_t a = h[k] | (h[k] << 1) | (h[k] >> 1);
                if (k > 0) a |= h[k - 1] >> 63;
                if (k < 7) a |= h[k + 1] << 63;
                hspu[k] = a;
            }
        }
        if (lane == 63 && wave < 127) {
            #pragma unroll
            for (int k = 0; k < 8; ++k) h[k] = cload64(&buf[base + WPR + k]);
            #pragma unroll
            for (int k = 0; k < 8; ++k) {
                uint64_t a = h[k] | (h[k] << 1) | (h[k] >> 1);
                if (k > 0) a |= h[k - 1] >> 63;
                if (k < 7) a |= h[k + 1] << 63;
                hspd[k] = a;
            }
        }
    };
    load_halo();

    bool grewAny = false;
    for (int r = 0; r < NROUND; ++r) {
        bool grew = false;
        for (;;) {
            uint64_t sp[8];
            #pragma unroll
            for (int k = 0; k < 8; ++k) {
                uint64_t h = own[k] | (own[k] << 1) | (own[k] >> 1);
                if (k > 0) h |= own[k - 1] >> 63;
                if (k < 7) h |= own[k + 1] << 63;
                sp[k] = h;
            }
            uint64_t su[8], sd[8];
            #pragma unroll
            for (int k = 0; k < 8; ++k) {
                su[k] = shfl_up64(sp[k], 1);
                sd[k] = shfl_dn64(sp[k], 1);
            }
            if (lane == 0) {
                #pragma unroll
                for (int k = 0; k < 8; ++k) su[k] = hspu[k];
            }
            if (lane == 63) {
                #pragma unroll
                for (int k = 0; k < 8; ++k) sd[k] = hspd[k];
            }
            uint32_t ch = 0;
            #pragma unroll
            for (int k = 0; k < 8; ++k) {
                uint64_t acc = sp[k] | su[k] | sd[k];
                uint64_t nv = runfill(own[k] | (acc & wk[k]), wk[k]);
                ch |= (uint32_t)(nv != own[k]);
                own[k] = nv;
            }
            if (ch) grew = true;
            if (__ballot(ch ? 1 : 0) == 0ull) break;   // wave-uniform
        }
        grewAny |= grew;

        if (grew && lane == 0)
            __hip_atomic_store(&flags[r], 1, __ATOMIC_RELAXED, __HIP_MEMORY_SCOPE_AGENT);
        if (lane == 0 || lane == 63) {
            #pragma unroll
            for (int k = 0; k < 8; ++k) cstore64(&buf[base + k], own[k]);
        }
        __syncthreads();
        if (threadIdx.x == 0) {
            __hip_atomic_fetch_add(&flags[8 + r], 1, __ATOMIC_RELAXED, __HIP_MEMORY_SCOPE_AGENT);
            while (__hip_atomic_load(&flags[8 + r], __ATOMIC_RELAXED, __HIP_MEMORY_SCOPE_AGENT) < NBLK)
                __builtin_amdgcn_s_sleep(2);
        }
        __syncthreads();

        if (__hip_atomic_load(&flags[r], __ATOMIC_RELAXED, __HIP_MEMORY_SCOPE_AGENT) == 0)
            break;
        if (r + 1 < NROUND) load_halo();
    }

    if (__ballot(grewAny ? 1 : 0) != 0ull) {
        #pragma unroll
        for (int k = 0; k < 8; ++k) buf[base + k] = own[k];
    }
}

// Kernel 3: expand bitmap -> (16,3,512,512) f32 output in {-1,+1}, float4.
__global__ void k_out(const unsigned long long* __restrict__ result, float* __restrict__ out) {
    int t = blockIdx.x * blockDim.x + threadIdx.x;
    int b = t >> 16;
    int r = t & 65535;
    int h = r >> 7;
    int w = (r & 127) << 2;
    int y = (b << 9) + h;
    unsigned long long word = result[y * WPR + (w >> 6)];
    int sh = w & 63;
    float4 v;
    v.x = ((word >> (sh + 0)) & 1ull) ? 1.0f : -1.0f;
    v.y = ((word >> (sh + 1)) & 1ull) ? 1.0f : -1.0f;
    v.z = ((word >> (sh + 2)) & 1ull) ? 1.0f : -1.0f;
    v.w = ((word >> (sh + 3)) & 1ull) ? 1.0f : -1.0f;
    int base = (b * 3) << 18;
    int off = (h << 9) + w;
    *(float4*)&out[base + off] = v;
    *(float4*)&out[base + 262144 + off] = v;
    *(float4*)&out[base + 524288 + off] = v;
}

extern "C" void kernel_launch(void* const* d_in, const int* in_sizes, int n_in,
                              void* d_out, int out_size, void* d_ws, size_t ws_size,
                              hipStream_t stream) {
    const float* x = (const float*)d_in[0];
    float* out = (float*)d_out;
    char* ws = (char*)d_ws;

    unsigned long long* buf   = (unsigned long long*)(ws);
    unsigned long long* weakB = (unsigned long long*)(ws + 524288);
    int* flags                = (int*)(ws + 1048576);

    k_sobnms<<<2048, 256, 0, stream>>>(x, buf, weakB, flags);
    k_hyst<<<NBLK, 256, 0, stream>>>(weakB, buf, flags);
    k_out<<<4096, 256, 0, stream>>>(buf, out);
}

// Round 11
// 121.342 us; speedup vs baseline: 1.6126x; 1.0617x over previous
//
#include <hip/hip_runtime.h>
#include <stdint.h>

#define HH 8192           // B*H = 16*512 strip height
#define WW 512            // width
#define WPR 8             // uint64 words per row (512/64)
#define TG22F 0.4142135623730951f
#define NROUND 8          // cap; early-exits on convergence
#define NBLK 32           // hysteresis grid: 32 blocks x 256 rows each

// ---- workspace layout (bytes) ----
// packed u16 mag|dir<<12 : 8 MiB   @ 0
// buf (strong, in-place) : 512 KiB @ 8388608
// weak bitmap            : 512 KiB @ 8912896
// flags (16 ints)        : 64 B    @ 9437184
//   flags[0..7]  = per-round "grew" indicators
//   flags[8..15] = per-round grid-barrier arrive counters (single-use, no reset)

// Quantize. Input is uniform[-1,1): t = ((v+1)*0.5)*255 lies in [0,255.0], so
// cv2's floor+clip equals plain float->int truncation. Same expression order
// as the original verified to_img -> same bytes. (absmax=0 in rounds 8/9.)
__device__ __forceinline__ int to_img_i(float v) {
    return (int)((v + 1.0f) * 0.5f * 255.0f);
}

// Fill all bits of runs of `w` that contain at least one bit of `s`.
__device__ __forceinline__ uint64_t runfill(uint64_t s, uint64_t w) {
    uint64_t sw = s & w;
    uint64_t up = ((sw + w) ^ w) & w;
    uint64_t rs = __brevll(sw);
    uint64_t rw = __brevll(w);
    uint64_t dn = __brevll(((rs + rw) ^ rw) & rw);
    return up | dn | sw;
}

// 64-bit shuffles via two 32-bit halves (avoid 64-bit shfl overloads).
__device__ __forceinline__ uint64_t shfl_up64(uint64_t v, int d) {
    int lo = __shfl_up((int)(uint32_t)v, d, 64);
    int hi = __shfl_up((int)(uint32_t)(v >> 32), d, 64);
    return ((uint64_t)(uint32_t)hi << 32) | (uint32_t)lo;
}
__device__ __forceinline__ uint64_t shfl_dn64(uint64_t v, int d) {
    int lo = __shfl_down((int)(uint32_t)v, d, 64);
    int hi = __shfl_down((int)(uint32_t)(v >> 32), d, 64);
    return ((uint64_t)(uint32_t)hi << 32) | (uint32_t)lo;
}

// coherent (cache-bypassing) 64-bit load/store at agent scope, no fences
__device__ __forceinline__ uint64_t cload64(const unsigned long long* p) {
    return __hip_atomic_load((const unsigned long long*)p, __ATOMIC_RELAXED,
                             __HIP_MEMORY_SCOPE_AGENT);
}
__device__ __forceinline__ void cstore64(unsigned long long* p, uint64_t v) {
    __hip_atomic_store(p, (unsigned long long)v, __ATOMIC_RELAXED,
                       __HIP_MEMORY_SCOPE_AGENT);
}

// horizontal 8-connected spread of one 512-px bit-row
__device__ __forceinline__ void spread8(const uint64_t h[8], uint64_t o[8]) {
    #pragma unroll
    for (int k = 0; k < 8; ++k) {
        uint64_t a = h[k] | (h[k] << 1) | (h[k] >> 1);
        if (k > 0) a |= h[k - 1] >> 63;
        if (k < 7) a |= h[k + 1] << 63;
        o[k] = a;
    }
}

// load 10 quantized pixels (cols 8*lane-1 .. 8*lane+8, edge-replicated) of
// one channel/row into a[0..9]. Two coalesced float4 loads + 2 shuffles.
__device__ __forceinline__ void load_row10(const float* __restrict__ in,
                                           int row, int c, int lane, int a[10]) {
    const float* p = &in[(size_t)((((row >> 9) * 3 + c) << 9) + (row & 511)) << 9];
    const int x0 = lane << 3;
    float4 v0 = *(const float4*)&p[x0];
    float4 v1 = *(const float4*)&p[x0 + 4];
    a[1] = to_img_i(v0.x);
    a[2] = to_img_i(v0.y);
    a[3] = to_img_i(v0.z);
    a[4] = to_img_i(v0.w);
    a[5] = to_img_i(v1.x);
    a[6] = to_img_i(v1.y);
    a[7] = to_img_i(v1.z);
    a[8] = to_img_i(v1.w);
    int l = __shfl_up(a[8], 1, 64);
    a[0] = (lane == 0) ? a[1] : l;      // col -1 -> replicate col 0
    int r = __shfl_down(a[1], 1, 64);
    a[9] = (lane == 63) ? a[8] : r;     // col 512 -> replicate col 511
}

// Kernel 1: quantize + Sobel + channel argmax + dir, one WAVE per image row,
// 8 px/lane, registers only (round-7 verified structure; to_img_i quantize).
__global__ void __launch_bounds__(256) k_sobel(const float* __restrict__ in,
                                               uint16_t* __restrict__ packed) {
    const int lane = threadIdx.x & 63;
    const int y  = (blockIdx.x << 2) + (threadIdx.x >> 6);
    const int ym = (y > 0) ? y - 1 : 0;
    const int yp = (y < HH - 1) ? y + 1 : HH - 1;

    int bestMag[8], bgx[8], bgy[8];
    #pragma unroll
    for (int j = 0; j < 8; ++j) { bestMag[j] = -1; bgx[j] = 0; bgy[j] = 0; }

    #pragma unroll
    for (int c = 0; c < 3; ++c) {
        int a0[10], a1[10], a2[10];
        load_row10(in, ym, c, lane, a0);
        load_row10(in, y,  c, lane, a1);
        load_row10(in, yp, c, lane, a2);
        int vs[10];
        #pragma unroll
        for (int i = 0; i < 10; ++i) vs[i] = a0[i] + 2 * a1[i] + a2[i];
        #pragma unroll
        for (int j = 0; j < 8; ++j) {
            int gx = vs[j + 2] - vs[j];
            int gy = (a2[j] + 2 * a2[j + 1] + a2[j + 2]) - (a0[j] + 2 * a0[j + 1] + a0[j + 2]);
            int mg = abs(gx) + abs(gy);
            if (mg > bestMag[j]) { bestMag[j] = mg; bgx[j] = gx; bgy[j] = gy; }
        }
    }

    uint32_t res[4];
    #pragma unroll
    for (int jj = 0; jj < 4; ++jj) {
        uint32_t pair = 0;
        #pragma unroll
        for (int s = 0; s < 2; ++s) {
            int j = jj * 2 + s;
            float axf = (float)abs(bgx[j]);
            float ayf = (float)abs(bgy[j]);
            int dir;
            if (ayf < TG22F * axf)      dir = 0;
            else if (ayf * TG22F > axf) dir = 1;
            else                        dir = (bgx[j] * bgy[j] >= 0) ? 2 : 3;
            uint32_t val = (uint32_t)(bestMag[j] | (dir << 12));
            pair |= val << (s * 16);
        }
        res[jj] = pair;
    }
    *(uint4*)&packed[y * WW + (lane << 3)] = *(uint4*)res;
}

// extract mag (12 bits) of px idx (0..7, compile-time) from a row quad (lo,hi)
#define MEXT(lo, hi, idx) ((int)((((idx) < 4 ? ((lo) >> (16 * (idx))) \
                                             : ((hi) >> (16 * ((idx) - 4))))) & 0xFFF))

// Kernel 2: NMS, one wave per image row, 8 px per lane. (verbatim round-5/7)
__global__ void k_nms(const uint16_t* __restrict__ packed,
                      unsigned long long* __restrict__ strongB,
                      unsigned long long* __restrict__ weakB,
                      int* __restrict__ flags) {
    if (blockIdx.x == 0 && threadIdx.x < 16) flags[threadIdx.x] = 0;
    const int lane = threadIdx.x & 63;
    const int w = threadIdx.x >> 6;
    const int y = (blockIdx.x << 2) + w;

    uint4 q = *(const uint4*)&packed[y * WW + (lane << 3)];
    uint64_t oLo = ((uint64_t)q.y << 32) | q.x;
    uint64_t oHi = ((uint64_t)q.w << 32) | q.z;
    uint64_t uLo = 0, uHi = 0, dLo = 0, dHi = 0;
    if (y > 0) {
        uint4 qu = *(const uint4*)&packed[(y - 1) * WW + (lane << 3)];
        uLo = ((uint64_t)qu.y << 32) | qu.x;
        uHi = ((uint64_t)qu.w << 32) | qu.z;
    }
    if (y < HH - 1) {
        uint4 qd = *(const uint4*)&packed[(y + 1) * WW + (lane << 3)];
        dLo = ((uint64_t)qd.y << 32) | qd.x;
        dHi = ((uint64_t)qd.w << 32) | qd.z;
    }

    int oL = __shfl_up((int)((oHi >> 48) & 0xFFF), 1, 64); if (lane == 0) oL = 0;
    int uL = __shfl_up((int)((uHi >> 48) & 0xFFF), 1, 64); if (lane == 0) uL = 0;
    int dL = __shfl_up((int)((dHi >> 48) & 0xFFF), 1, 64); if (lane == 0) dL = 0;
    int oR = __shfl_down((int)(oLo & 0xFFF), 1, 64); if (lane == 63) oR = 0;
    int uR = __shfl_down((int)(uLo & 0xFFF), 1, 64); if (lane == 63) uR = 0;
    int dR = __shfl_down((int)(dLo & 0xFFF), 1, 64); if (lane == 63) dR = 0;

    uint32_t sb = 0, wb = 0;
    #pragma unroll
    for (int i = 0; i < 8; ++i) {
        int raw = (int)(((i < 4 ? (oLo >> (16 * i)) : (oHi >> (16 * (i - 4))))) & 0xFFFF);
        int m = raw & 0xFFF;
        int dir = raw >> 12;
        int Om1 = (i == 0) ? oL : MEXT(oLo, oHi, (i == 0 ? 0 : i - 1));
        int Op1 = (i == 7) ? oR : MEXT(oLo, oHi, (i == 7 ? 7 : i + 1));
        int Ui  = MEXT(uLo, uHi, i);
        int Um1 = (i == 0) ? uL : MEXT(uLo, uHi, (i == 0 ? 0 : i - 1));
        int Up1 = (i == 7) ? uR : MEXT(uLo, uHi, (i == 7 ? 7 : i + 1));
        int Di  = MEXT(dLo, dHi, i);
        int Dm1 = (i == 0) ? dL : MEXT(dLo, dHi, (i == 0 ? 0 : i - 1));
        int Dp1 = (i == 7) ? dR : MEXT(dLo, dHi, (i == 7 ? 7 : i + 1));
        // dir0:(0,-1) dir1:(-1,0) dir2:(-1,-1) dir3:(-1,+1); n1=+d1, n2=-d1
        int n1 = (dir == 0) ? Om1 : (dir == 1) ? Ui : (dir == 2) ? Um1 : Up1;
        int n2 = (dir == 0) ? Op1 : (dir == 1) ? Di : (dir == 2) ? Dp1 : Dm1;
        bool keep = (m > n1) && (m >= n2);
        if (keep && m > 200) sb |= 1u << i;
        if (keep && m > 100) wb |= 1u << i;
    }

    const int src = (lane & 7) << 3;
    uint64_t wordS = 0, wordW = 0;
    #pragma unroll
    for (int i = 0; i < 8; ++i) {
        wordS |= (uint64_t)(uint32_t)__shfl((int)sb, src + i, 64) << (i * 8);
        wordW |= (uint64_t)(uint32_t)__shfl((int)wb, src + i, 64) << (i * 8);
    }
    if (lane < 8)       strongB[y * WPR + lane] = wordS;
    else if (lane < 16) weakB[y * WPR + (lane - 8)] = wordW;
}

// Kernel 3: hierarchical hysteresis, 256-row blocks (round-10 structure with
// the wave-growth reduction FIXED: all growth tests are ballot-reduced
// wave-wide before driving chFlag/roundGrew/grewAny/flags -- round 10 lost
// interior growth because per-lane `grew` was tested on lane 0 only, which
// skipped the final writeback for blocks whose lane-0 rows never changed).
__global__ void __launch_bounds__(256) k_hyst(
        const unsigned long long* __restrict__ weakB,
        unsigned long long* __restrict__ buf,
        int* __restrict__ flags)
{
    __shared__ uint64_t topRow[4][8];   // per-wave lane-0 (top) row
    __shared__ uint64_t botRow[4][8];   // per-wave lane-63 (bottom) row
    __shared__ int chFlag;

    const int lane = threadIdx.x & 63;
    const int wid  = threadIdx.x >> 6;           // wave in block 0..3
    const int gw   = (blockIdx.x << 2) + wid;    // global wave 0..127
    const int base = ((gw << 6) + lane) * WPR;   // own row

    uint64_t own[8], wk[8];
    #pragma unroll
    for (int k = 0; k < 8; ++k) { wk[k] = weakB[base + k]; own[k] = buf[base + k]; }

    bool grewAny = false;                        // block-uniform

    for (int r = 0; r < NROUND; ++r) {
        // cross-block halo (coherent loads from neighbor blocks' edge rows),
        // static for this global round. Only two threads per block use it.
        uint64_t extsp[8];
        #pragma unroll
        for (int k = 0; k < 8; ++k) extsp[k] = 0;
        if (wid == 0 && lane == 0 && blockIdx.x > 0) {
            uint64_t h[8];
            #pragma unroll
            for (int k = 0; k < 8; ++k) h[k] = cload64(&buf[base - WPR + k]);
            spread8(h, extsp);
        }
        if (wid == 3 && lane == 63 && blockIdx.x < NBLK - 1) {
            uint64_t h[8];
            #pragma unroll
            for (int k = 0; k < 8; ++k) h[k] = cload64(&buf[base + WPR + k]);
            spread8(h, extsp);
        }

        // ---- intra-block convergence: LDS halo passes ----
        bool roundGrew = false;                  // block-uniform
        for (;;) {
            __syncthreads();                        // (A) protect LDS reuse
            if (threadIdx.x == 0) chFlag = 0;
            if (lane == 0) {
                #pragma unroll
                for (int k = 0; k < 8; ++k) topRow[wid][k] = own[k];
            }
            if (lane == 63) {
                #pragma unroll
                for (int k = 0; k < 8; ++k) botRow[wid][k] = own[k];
            }
            __syncthreads();                        // (B) rows + reset visible

            uint64_t hspu[8], hspd[8];
            #pragma unroll
            for (int k = 0; k < 8; ++k) { hspu[k] = 0; hspd[k] = 0; }
            if (lane == 0) {
                if (wid > 0) {
                    uint64_t h[8];
                    #pragma unroll
                    for (int k = 0; k < 8; ++k) h[k] = botRow[wid - 1][k];
                    spread8(h, hspu);
                } else {
                    #pragma unroll
                    for (int k = 0; k < 8; ++k) hspu[k] = extsp[k];
                }
            }
            if (lane == 63) {
                if (wid < 3) {
                    uint64_t h[8];
                    #pragma unroll
                    for (int k = 0; k < 8; ++k) h[k] = topRow[wid + 1][k];
                    spread8(h, hspd);
                } else {
                    #pragma unroll
                    for (int k = 0; k < 8; ++k) hspd[k] = extsp[k];
                }
            }

            // wave-local converge (verbatim verified inner loop)
            bool grew = false;                      // per-lane
            for (;;) {
                uint64_t sp[8];
                spread8(own, sp);
                uint64_t su[8], sd[8];
                #pragma unroll
                for (int k = 0; k < 8; ++k) {
                    su[k] = shfl_up64(sp[k], 1);
                    sd[k] = shfl_dn64(sp[k], 1);
                }
                if (lane == 0) {
                    #pragma unroll
                    for (int k = 0; k < 8; ++k) su[k] = hspu[k];
                }
                if (lane == 63) {
                    #pragma unroll
                    for (int k = 0; k < 8; ++k) sd[k] = hspd[k];
                }
                uint32_t ch = 0;
                #pragma unroll
                for (int k = 0; k < 8; ++k) {
                    uint64_t acc = sp[k] | su[k] | sd[k];
                    uint64_t nv = runfill(own[k] | (acc & wk[k]), wk[k]);
                    ch |= (uint32_t)(nv != own[k]);
                    own[k] = nv;
                }
                if (ch) grew = true;
                if (__ballot(ch ? 1 : 0) == 0ull) break;   // wave-uniform
            }

            // FIX: reduce growth wave-wide BEFORE driving the block flag
            bool waveGrew = (__ballot(grew ? 1 : 0) != 0ull);  // wave-uniform
            if (waveGrew && lane == 0) chFlag = 1;  // benign same-value race
            __syncthreads();                        // (C) flag settled
            if (chFlag == 0) break;                 // block converged
            roundGrew = true;
        }
        grewAny |= roundGrew;

        // ---- publish block edge rows + growth flag, then grid barrier ----
        if (roundGrew && threadIdx.x == 0)
            __hip_atomic_store(&flags[r], 1, __ATOMIC_RELAXED, __HIP_MEMORY_SCOPE_AGENT);
        if ((wid == 0 && lane == 0) || (wid == 3 && lane == 63)) {
            #pragma unroll
            for (int k = 0; k < 8; ++k) cstore64(&buf[base + k], own[k]);
        }
        __syncthreads();   // vmcnt(0) drain: stores visible before arrive
        if (threadIdx.x == 0) {
            __hip_atomic_fetch_add(&flags[8 + r], 1, __ATOMIC_RELAXED, __HIP_MEMORY_SCOPE_AGENT);
            while (__hip_atomic_load(&flags[8 + r], __ATOMIC_RELAXED, __HIP_MEMORY_SCOPE_AGENT) < NBLK)
                __builtin_amdgcn_s_sleep(2);
        }
        __syncthreads();

        if (__hip_atomic_load(&flags[r], __ATOMIC_RELAXED, __HIP_MEMORY_SCOPE_AGENT) == 0)
            break;
    }

    // final writeback (grewAny is block-uniform; unchanged blocks match buf)
    if (grewAny) {
        #pragma unroll
        for (int k = 0; k < 8; ++k) buf[base + k] = own[k];
    }
}

// Kernel 4: expand bitmap -> (16,3,512,512) f32 output in {-1,+1}, float4.
__global__ void k_out(const unsigned long long* __restrict__ result, float* __restrict__ out) {
    int t = blockIdx.x * blockDim.x + threadIdx.x;
    int b = t >> 16;
    int r = t & 65535;
    int h = r >> 7;
    int w = (r & 127) << 2;
    int y = (b << 9) + h;
    unsigned long long word = result[y * WPR + (w >> 6)];
    int sh = w & 63;
    float4 v;
    v.x = ((word >> (sh + 0)) & 1ull) ? 1.0f : -1.0f;
    v.y = ((word >> (sh + 1)) & 1ull) ? 1.0f : -1.0f;
    v.z = ((word >> (sh + 2)) & 1ull) ? 1.0f : -1.0f;
    v.w = ((word >> (sh + 3)) & 1ull) ? 1.0f : -1.0f;
    int base = (b * 3) << 18;
    int off = (h << 9) + w;
    *(float4*)&out[base + off] = v;
    *(float4*)&out[base + 262144 + off] = v;
    *(float4*)&out[base + 524288 + off] = v;
}

extern "C" void kernel_launch(void* const* d_in, const int* in_sizes, int n_in,
                              void* d_out, int out_size, void* d_ws, size_t ws_size,
                              hipStream_t stream) {
    const float* x = (const float*)d_in[0];
    float* out = (float*)d_out;
    char* ws = (char*)d_ws;

    uint16_t* packed          = (uint16_t*)(ws);
    unsigned long long* buf   = (unsigned long long*)(ws + 8388608);
    unsigned long long* weakB = (unsigned long long*)(ws + 8912896);
    int* flags                = (int*)(ws + 9437184);

    k_sobel<<<2048, 256, 0, stream>>>(x, packed);
    k_nms<<<2048, 256, 0, stream>>>(packed, buf, weakB, flags);
    k_hyst<<<NBLK, 256, 0, stream>>>(weakB, buf, flags);
    k_out<<<4096, 256, 0, stream>>>(buf, out);
}